// Round 1
// baseline (242.962 us; speedup 1.0000x reference)
//
#include <hip/hip_runtime.h>

#define BB 8
#define CC 64
#define HH 256
#define WW 256
#define DSF 8
#define HP 32
#define WP 32
#define NN 1024  // HP*WP

// ---------------------------------------------------------------------------
// K1: 8x8 avg-pool of both diff and x.
// One block per (src, b, c, ph) strip of 8 rows x 256 cols.
// Fully coalesced: each thread reads 2 float4 from the flattened [8][64xfloat4]
// strip, partial-sums in LDS, 32 threads finish the 32 pooled outputs.
// ---------------------------------------------------------------------------
__global__ __launch_bounds__(256) void k_pool(const float* __restrict__ x,
                                              const float* __restrict__ diff,
                                              float* __restrict__ dpool,
                                              float* __restrict__ pxpool) {
    __shared__ float sums[256];
    int bid = blockIdx.x;
    int which = bid >> 14;            // 0 = diff, 1 = x    (2*8*64*32 = 32768 blocks)
    int r = bid & 16383;
    int ph = r & 31;
    int c = (r >> 5) & 63;
    int b = r >> 11;
    const float* src = which ? x : diff;
    float* dst = which ? pxpool : dpool;
    const float* base = src + ((size_t)(b * CC + c) * HH + ph * DSF) * WW;
    int t = threadIdx.x;
    float s = 0.f;
#pragma unroll
    for (int kk = 0; kk < 2; ++kk) {
        int idx = t + kk * 256;       // [0,512): rr = idx>>6 (row), j = idx&63 (float4 col)
        int rr = idx >> 6;
        int j = idx & 63;
        float4 v = *(const float4*)(base + rr * WW + j * 4);
        s += v.x + v.y + v.z + v.w;
    }
    sums[t] = s;
    __syncthreads();
    if (t < 32) {
        // pool col t gets contributions from j in {2t, 2t+1}, rr in {0..3}
        float acc = 0.f;
#pragma unroll
        for (int rr = 0; rr < 4; ++rr)
            acc += sums[rr * 64 + 2 * t] + sums[rr * 64 + 2 * t + 1];
        dst[(size_t)(b * CC + c) * NN + ph * WP + t] = acc * (1.f / 64.f);
    }
}

// ---------------------------------------------------------------------------
// K2: q/k/v = W @ pooled + b.  grid.x = 3 * B * (N/64) = 384.
// Per block: stage W (64x64, pad 65) and a 64-token tile (pad 68) in LDS;
// each thread computes 16 outputs (one o, 16 n) with float4 accumulation.
// ---------------------------------------------------------------------------
__global__ __launch_bounds__(256) void k_proj(const float* __restrict__ dpool,
                                              const float* __restrict__ pxpool,
                                              const float* __restrict__ Wq, const float* __restrict__ bq,
                                              const float* __restrict__ Wk, const float* __restrict__ bk,
                                              const float* __restrict__ Wv, const float* __restrict__ bv,
                                              float* __restrict__ q, float* __restrict__ k,
                                              float* __restrict__ v) {
    __shared__ float Ws[64 * 65];
    __shared__ float dsh[64 * 68];
    int bid = blockIdx.x;
    int proj = bid >> 7;              // / 128
    int rem = bid & 127;
    int b = rem >> 4;
    int n0 = (rem & 15) * 64;
    const float* Wm; const float* bias; float* out; const float* src;
    if (proj == 0)      { Wm = Wq; bias = bq; out = q; src = dpool; }
    else if (proj == 1) { Wm = Wk; bias = bk; out = k; src = dpool; }
    else                { Wm = Wv; bias = bv; out = v; src = pxpool; }
    int t = threadIdx.x;
#pragma unroll
    for (int i = 0; i < 16; ++i) {
        int e = t + i * 256;
        int o = e >> 6, c = e & 63;
        Ws[o * 65 + c] = Wm[e];
        dsh[o * 68 + c] = src[(size_t)(b * CC + o) * NN + n0 + c];  // o==channel, c==n-local
    }
    __syncthreads();
    int o = t & 63;
    int ng = t >> 6;                  // wave id; all lanes in a wave share ng
    float bb = bias[o];
    float4 acc[4];
#pragma unroll
    for (int j = 0; j < 4; ++j) acc[j] = make_float4(bb, bb, bb, bb);
#pragma unroll 8
    for (int c = 0; c < 64; ++c) {
        float wv = Ws[o * 65 + c];
        const float4* dr = (const float4*)(dsh + c * 68 + ng * 16);
#pragma unroll
        for (int j = 0; j < 4; ++j) {
            float4 d4 = dr[j];
            acc[j].x += wv * d4.x; acc[j].y += wv * d4.y;
            acc[j].z += wv * d4.z; acc[j].w += wv * d4.w;
        }
    }
    float4* ob = (float4*)(out + (size_t)(b * CC + o) * NN + n0 + ng * 16);
#pragma unroll
    for (int j = 0; j < 4; ++j) ob[j] = acc[j];
}

// ---------------------------------------------------------------------------
// K3: fused attention for one (batch, 8-query-row) tile. grid.x = 8*128 = 1024.
//  a) q tile (scaled) -> LDS
//  b) energy rows (8 x 1024) -> LDS (padded stride 1028)
//  c) exact softmax per row (wave shuffle reduce), P stored back in LDS
//  d) PV: 4 waves split m-range, each thread 4c x 2nl register tile,
//     partials reduced through LDS (stride 9 to dodge bank conflicts)
// ---------------------------------------------------------------------------
__global__ __launch_bounds__(256) void k_attn(const float* __restrict__ q,
                                              const float* __restrict__ k,
                                              const float* __restrict__ v,
                                              float* __restrict__ op) {
    const int NT = 8;
    __shared__ float qs[64 * NT];          // qs[c*8+nl], pre-scaled by C^-0.5
    __shared__ float es[NT * 1028];        // es[nl*1028+m]
    __shared__ float part[4 * 64 * 9];     // part[(g*64+c)*9+nl]
    __shared__ float linv[NT];
    int bid = blockIdx.x;
    int b = bid >> 7;
    int n0 = (bid & 127) * NT;
    int t = threadIdx.x;

#pragma unroll
    for (int i = 0; i < 2; ++i) {
        int e = t + i * 256;               // 512 elements
        int c = e >> 3, nl = e & 7;
        qs[c * 8 + nl] = q[(size_t)(b * CC + c) * NN + n0 + nl] * 0.125f;
    }
    __syncthreads();

    // --- energy ---
    const float4* qsp = (const float4*)qs;
#pragma unroll
    for (int mc = 0; mc < 4; ++mc) {
        int m = mc * 256 + t;
        const float* kp = k + (size_t)b * CC * NN + m;
        float4 a0 = make_float4(0, 0, 0, 0), a1 = make_float4(0, 0, 0, 0);
#pragma unroll 8
        for (int c = 0; c < 64; ++c) {
            float kv = kp[(size_t)c * NN];
            float4 q0 = qsp[c * 2], q1 = qsp[c * 2 + 1];
            a0.x += kv * q0.x; a0.y += kv * q0.y; a0.z += kv * q0.z; a0.w += kv * q0.w;
            a1.x += kv * q1.x; a1.y += kv * q1.y; a1.z += kv * q1.z; a1.w += kv * q1.w;
        }
        es[0 * 1028 + m] = a0.x; es[1 * 1028 + m] = a0.y;
        es[2 * 1028 + m] = a0.z; es[3 * 1028 + m] = a0.w;
        es[4 * 1028 + m] = a1.x; es[5 * 1028 + m] = a1.y;
        es[6 * 1028 + m] = a1.z; es[7 * 1028 + m] = a1.w;
    }
    __syncthreads();

    // --- softmax (wave w handles rows 2w, 2w+1) ---
    int wave = t >> 6, lane = t & 63;
#pragma unroll
    for (int rr = 0; rr < 2; ++rr) {
        int nl = wave * 2 + rr;
        float* row = es + nl * 1028;
        float vals[16];
        float mx = -1e30f;
#pragma unroll
        for (int j = 0; j < 16; ++j) { vals[j] = row[lane + 64 * j]; mx = fmaxf(mx, vals[j]); }
#pragma unroll
        for (int off = 32; off; off >>= 1) mx = fmaxf(mx, __shfl_xor(mx, off));
        float sum = 0.f;
#pragma unroll
        for (int j = 0; j < 16; ++j) {
            float p = __expf(vals[j] - mx);
            row[lane + 64 * j] = p;
            sum += p;
        }
#pragma unroll
        for (int off = 32; off; off >>= 1) sum += __shfl_xor(sum, off);
        if (lane == 0) linv[nl] = 1.f / sum;
    }
    __syncthreads();

    // --- PV ---
    int g = wave;                          // m-range [g*256, g*256+256)
    int u = lane;
    int c0 = (u & 15) * 4;
    int nlh = u >> 4;                      // 0..3
    int nl0 = nlh * 2;
    float acc[4][2] = {};
    const float4* vb = (const float4*)(v + (size_t)b * CC * NN);
    const float4* e0 = (const float4*)(es + nl0 * 1028);
    const float4* e1 = (const float4*)(es + (nl0 + 1) * 1028);
#pragma unroll 4
    for (int mm4 = 0; mm4 < 64; ++mm4) {
        int m4 = g * 64 + mm4;
        float4 p0 = e0[m4], p1 = e1[m4];
#pragma unroll
        for (int i = 0; i < 4; ++i) {
            float4 vv = vb[(size_t)(c0 + i) * 256 + m4];
            acc[i][0] += vv.x * p0.x + vv.y * p0.y + vv.z * p0.z + vv.w * p0.w;
            acc[i][1] += vv.x * p1.x + vv.y * p1.y + vv.z * p1.z + vv.w * p1.w;
        }
    }
#pragma unroll
    for (int i = 0; i < 4; ++i) {
        part[(g * 64 + c0 + i) * 9 + nl0] = acc[i][0];
        part[(g * 64 + c0 + i) * 9 + nl0 + 1] = acc[i][1];
    }
    __syncthreads();
#pragma unroll
    for (int i = 0; i < 2; ++i) {
        int e = t * 2 + i;                 // 512 outputs: c = e>>3, nl = e&7
        int c = e >> 3, nl = e & 7;
        float s = part[(0 * 64 + c) * 9 + nl] + part[(1 * 64 + c) * 9 + nl] +
                  part[(2 * 64 + c) * 9 + nl] + part[(3 * 64 + c) * 9 + nl];
        op[(size_t)(b * CC + c) * NN + n0 + nl] = s * linv[nl];
    }
}

// ---------------------------------------------------------------------------
// K4: out = nearest-upsample(op, 8) + x.  Pure streaming float4.
// ---------------------------------------------------------------------------
__global__ __launch_bounds__(256) void k_out(const float* __restrict__ x,
                                             const float* __restrict__ op,
                                             float* __restrict__ out) {
    size_t gid = (size_t)blockIdx.x * 256 + threadIdx.x;
    size_t flat = gid * 4;
    int w = (int)(flat & 255);
    int h = (int)((flat >> 8) & 255);
    int bc = (int)(flat >> 16);
    float ov = op[(size_t)bc * NN + (h >> 3) * WP + (w >> 3)];
    float4 xv = *(const float4*)(x + flat);
    float4 r;
    r.x = xv.x + ov; r.y = xv.y + ov; r.z = xv.z + ov; r.w = xv.w + ov;
    *(float4*)(out + flat) = r;
}

extern "C" void kernel_launch(void* const* d_in, const int* in_sizes, int n_in,
                              void* d_out, int out_size, void* d_ws, size_t ws_size,
                              hipStream_t stream) {
    const float* x    = (const float*)d_in[0];
    const float* diff = (const float*)d_in[1];
    const float* Wq   = (const float*)d_in[2];
    const float* bq   = (const float*)d_in[3];
    const float* Wk   = (const float*)d_in[4];
    const float* bk   = (const float*)d_in[5];
    const float* Wv   = (const float*)d_in[6];
    const float* bv   = (const float*)d_in[7];
    float* ws = (float*)d_ws;
    // workspace layout (floats): d, px, q, k, v, op  (each B*C*N = 524288)
    float* dpool  = ws;
    float* pxpool = ws + 524288;
    float* q      = ws + 1048576;
    float* k      = ws + 1572864;
    float* v      = ws + 2097152;
    float* op     = ws + 2621440;
    float* out = (float*)d_out;

    hipLaunchKernelGGL(k_pool, dim3(32768), dim3(256), 0, stream, x, diff, dpool, pxpool);
    hipLaunchKernelGGL(k_proj, dim3(384), dim3(256), 0, stream, dpool, pxpool,
                       Wq, bq, Wk, bk, Wv, bv, q, k, v);
    hipLaunchKernelGGL(k_attn, dim3(1024), dim3(256), 0, stream, q, k, v, op);
    hipLaunchKernelGGL(k_out, dim3(32768), dim3(256), 0, stream, x, op, out);
}

// Round 2
// 135.067 us; speedup vs baseline: 1.7988x; 1.7988x over previous
//
#include <hip/hip_runtime.h>

#define BB 8
#define CC 64
#define HH 256
#define WW 256
#define DSF 8
#define HP 32
#define WP 32
#define NN 1024  // HP*WP

typedef _Float16 f16x4 __attribute__((ext_vector_type(4)));
typedef float f32x4 __attribute__((ext_vector_type(4)));

// ---------------------------------------------------------------------------
// K1: 8x8 avg-pool of both diff and x (unchanged from R0 — coalesced float4).
// ---------------------------------------------------------------------------
__global__ __launch_bounds__(256) void k_pool(const float* __restrict__ x,
                                              const float* __restrict__ diff,
                                              float* __restrict__ dpool,
                                              float* __restrict__ pxpool) {
    __shared__ float sums[256];
    int bid = blockIdx.x;
    int which = bid >> 14;            // 0 = diff, 1 = x
    int r = bid & 16383;
    int ph = r & 31;
    int c = (r >> 5) & 63;
    int b = r >> 11;
    const float* src = which ? x : diff;
    float* dst = which ? pxpool : dpool;
    const float* base = src + ((size_t)(b * CC + c) * HH + ph * DSF) * WW;
    int t = threadIdx.x;
    float s = 0.f;
#pragma unroll
    for (int kk = 0; kk < 2; ++kk) {
        int idx = t + kk * 256;
        int rr = idx >> 6;
        int j = idx & 63;
        float4 v = *(const float4*)(base + rr * WW + j * 4);
        s += v.x + v.y + v.z + v.w;
    }
    sums[t] = s;
    __syncthreads();
    if (t < 32) {
        float acc = 0.f;
#pragma unroll
        for (int rr = 0; rr < 4; ++rr)
            acc += sums[rr * 64 + 2 * t] + sums[rr * 64 + 2 * t + 1];
        dst[(size_t)(b * CC + c) * NN + ph * WP + t] = acc * (1.f / 64.f);
    }
}

// ---------------------------------------------------------------------------
// K2: projections -> f16 in MFMA-friendly layouts.
//   q_t[b][n][c] f16, pre-scaled by C^-0.5   (via LDS transpose)
//   k_t[b][m][c] f16                         (via LDS transpose)
//   v_ct[b][c][m] f16                        (direct, contiguous)
// grid.x = 3*B*(N/64) = 384.
// ---------------------------------------------------------------------------
__global__ __launch_bounds__(256) void k_proj(const float* __restrict__ dpool,
                                              const float* __restrict__ pxpool,
                                              const float* __restrict__ Wq, const float* __restrict__ bq,
                                              const float* __restrict__ Wk, const float* __restrict__ bk,
                                              const float* __restrict__ Wv, const float* __restrict__ bv,
                                              _Float16* __restrict__ qt, _Float16* __restrict__ kt,
                                              _Float16* __restrict__ vct) {
    __shared__ float Ws[64 * 65];
    __shared__ float dsh[64 * 68];
    int bid = blockIdx.x;
    int proj = bid >> 7;
    int rem = bid & 127;
    int b = rem >> 4;
    int n0 = (rem & 15) * 64;
    const float* Wm; const float* bias; const float* src;
    if (proj == 0)      { Wm = Wq; bias = bq; src = dpool; }
    else if (proj == 1) { Wm = Wk; bias = bk; src = dpool; }
    else                { Wm = Wv; bias = bv; src = pxpool; }
    int t = threadIdx.x;
#pragma unroll
    for (int i = 0; i < 16; ++i) {
        int e = t + i * 256;
        int o = e >> 6, c = e & 63;
        Ws[o * 65 + c] = Wm[e];
        dsh[o * 68 + c] = src[(size_t)(b * CC + o) * NN + n0 + c];
    }
    __syncthreads();
    int o = t & 63;
    int ng = t >> 6;
    float bb = bias[o];
    float4 acc[4];
#pragma unroll
    for (int j = 0; j < 4; ++j) acc[j] = make_float4(bb, bb, bb, bb);
#pragma unroll 8
    for (int c = 0; c < 64; ++c) {
        float wv = Ws[o * 65 + c];
        const float4* dr = (const float4*)(dsh + c * 68 + ng * 16);
#pragma unroll
        for (int j = 0; j < 4; ++j) {
            float4 d4 = dr[j];
            acc[j].x += wv * d4.x; acc[j].y += wv * d4.y;
            acc[j].z += wv * d4.z; acc[j].w += wv * d4.w;
        }
    }
    if (proj == 2) {
        // v: [c][m] f16, 16 contiguous halves per thread
        _Float16* outp = vct + (size_t)(b * CC + o) * NN + n0 + ng * 16;
#pragma unroll
        for (int j = 0; j < 4; ++j) {
            f16x4 h;
            h[0] = (_Float16)acc[j].x; h[1] = (_Float16)acc[j].y;
            h[2] = (_Float16)acc[j].z; h[3] = (_Float16)acc[j].w;
            *(f16x4*)(outp + 4 * j) = h;
        }
    } else {
        // q/k: transpose through LDS to [n][c] f16
        __syncthreads();   // everyone done reading dsh
#pragma unroll
        for (int j = 0; j < 4; ++j)
            *(float4*)(&dsh[o * 68 + ng * 16 + 4 * j]) = acc[j];
        __syncthreads();
        int nl = t & 63, og = t >> 6;
        float scale = (proj == 0) ? 0.125f : 1.0f;
        _Float16* outp = (proj == 0 ? qt : kt) + (size_t)(b * NN + n0 + nl) * CC + og * 16;
#pragma unroll
        for (int jj = 0; jj < 4; ++jj) {
            f16x4 h;
#pragma unroll
            for (int q4 = 0; q4 < 4; ++q4)
                h[q4] = (_Float16)(dsh[(og * 16 + 4 * jj + q4) * 68 + nl] * scale);
            *(f16x4*)(outp + 4 * jj) = h;
        }
    }
}

// ---------------------------------------------------------------------------
// K3: MFMA attention. One block = (b, 16-query tile). grid.x = 8*64 = 512.
// 4 waves, wave w owns m-range [256w, 256w+256).
//   energy: v_mfma_f32_16x16x16_f16, A=q_t rows, B=k_t cols (16 m-tiles x 4 kc)
//   softmax: 16-lane shuffle reduce + cross-wave LDS max; unnormalized exp
//   P -> LDS f16 (wave reads back only its own region)
//   PV: MFMA A=P, B=v_ct; cross-wave partials via LDS; normalize in epilogue
// ---------------------------------------------------------------------------
__global__ __launch_bounds__(256) void k_attn(const _Float16* __restrict__ qt,
                                              const _Float16* __restrict__ kt,
                                              const _Float16* __restrict__ vct,
                                              float* __restrict__ op) {
#define PS 1036
    __shared__ __align__(16) _Float16 P[16 * PS];
    __shared__ float part[4 * 16 * 65];
    __shared__ float wmax[4][16];
    __shared__ float wsum[4][16];
    int bid = blockIdx.x;
    int b = bid >> 6;
    int n0 = (bid & 63) * 16;
    int t = threadIdx.x;
    int w = t >> 6, l = t & 63;
    int lo = l & 15, g = l >> 4;

    const _Float16* qb = qt + (size_t)(b * NN + n0) * CC;
    const _Float16* kb = kt + (size_t)b * NN * CC;
    const _Float16* vb = vct + (size_t)b * CC * NN;

    // q A-fragments: A[row=lo][c = 4g + jr + 16kc]
    f16x4 aq[4];
#pragma unroll
    for (int kc = 0; kc < 4; ++kc)
        aq[kc] = *(const f16x4*)(qb + lo * CC + 16 * kc + 4 * g);

    int mbase = w * 256;
    f32x4 e[16];
#pragma unroll
    for (int tm = 0; tm < 16; ++tm) e[tm] = (f32x4){0.f, 0.f, 0.f, 0.f};
#pragma unroll
    for (int tm = 0; tm < 16; ++tm) {
        int m = mbase + 16 * tm + lo;
        const _Float16* kr = kb + (size_t)m * CC + 4 * g;
#pragma unroll
        for (int kc = 0; kc < 4; ++kc) {
            f16x4 bk = *(const f16x4*)(kr + 16 * kc);
            e[tm] = __builtin_amdgcn_mfma_f32_16x16x16f16(aq[kc], bk, e[tm], 0, 0, 0);
        }
    }
    // lane holds E[n = 4g + r][m = lo + 16 tm + mbase]
    float mx[4], sm[4];
#pragma unroll
    for (int r = 0; r < 4; ++r) {
        float m_ = -1e30f;
#pragma unroll
        for (int tm = 0; tm < 16; ++tm) m_ = fmaxf(m_, e[tm][r]);
#pragma unroll
        for (int off = 8; off; off >>= 1) m_ = fmaxf(m_, __shfl_xor(m_, off));
        mx[r] = m_;
    }
    if (lo == 0) {
#pragma unroll
        for (int r = 0; r < 4; ++r) wmax[w][4 * g + r] = mx[r];
    }
    __syncthreads();
#pragma unroll
    for (int r = 0; r < 4; ++r) {
        int n = 4 * g + r;
        mx[r] = fmaxf(fmaxf(wmax[0][n], wmax[1][n]), fmaxf(wmax[2][n], wmax[3][n]));
        sm[r] = 0.f;
    }
#pragma unroll
    for (int tm = 0; tm < 16; ++tm) {
        int mcol = mbase + 16 * tm + lo;
#pragma unroll
        for (int r = 0; r < 4; ++r) {
            float p = __expf(e[tm][r] - mx[r]);
            sm[r] += p;
            P[(4 * g + r) * PS + mcol] = (_Float16)p;
        }
    }
#pragma unroll
    for (int r = 0; r < 4; ++r) {
#pragma unroll
        for (int off = 8; off; off >>= 1) sm[r] += __shfl_xor(sm[r], off);
    }
    if (lo == 0) {
#pragma unroll
        for (int r = 0; r < 4; ++r) wsum[w][4 * g + r] = sm[r];
    }
    // PV: wave reads P rows 0..15, cols [mbase, mbase+256) — its OWN writes only.
    f32x4 o4[4];
#pragma unroll
    for (int tc = 0; tc < 4; ++tc) o4[tc] = (f32x4){0.f, 0.f, 0.f, 0.f};
#pragma unroll
    for (int mk = 0; mk < 16; ++mk) {
        f16x4 pa = *(const f16x4*)(&P[lo * PS + mbase + 16 * mk + 4 * g]);
        const _Float16* vr = vb + mbase + 16 * mk + 4 * g;
#pragma unroll
        for (int tc = 0; tc < 4; ++tc) {
            f16x4 bv_ = *(const f16x4*)(vr + (size_t)(lo + 16 * tc) * NN);
            o4[tc] = __builtin_amdgcn_mfma_f32_16x16x16f16(pa, bv_, o4[tc], 0, 0, 0);
        }
    }
#pragma unroll
    for (int tc = 0; tc < 4; ++tc)
#pragma unroll
        for (int r = 0; r < 4; ++r)
            part[(w * 16 + 4 * g + r) * 65 + lo + 16 * tc] = o4[tc][r];
    __syncthreads();
#pragma unroll
    for (int i = 0; i < 4; ++i) {
        int e2 = t + i * 256;
        int c = e2 >> 4, n = e2 & 15;
        float s = part[(0 * 16 + n) * 65 + c] + part[(1 * 16 + n) * 65 + c] +
                  part[(2 * 16 + n) * 65 + c] + part[(3 * 16 + n) * 65 + c];
        float denom = wsum[0][n] + wsum[1][n] + wsum[2][n] + wsum[3][n];
        op[(size_t)(b * CC + c) * NN + n0 + n] = s / denom;
    }
#undef PS
}

// ---------------------------------------------------------------------------
// K4: out = nearest-upsample(op, 8) + x (unchanged).
// ---------------------------------------------------------------------------
__global__ __launch_bounds__(256) void k_out(const float* __restrict__ x,
                                             const float* __restrict__ op,
                                             float* __restrict__ out) {
    size_t gid = (size_t)blockIdx.x * 256 + threadIdx.x;
    size_t flat = gid * 4;
    int w = (int)(flat & 255);
    int h = (int)((flat >> 8) & 255);
    int bc = (int)(flat >> 16);
    float ov = op[(size_t)bc * NN + (h >> 3) * WP + (w >> 3)];
    float4 xv = *(const float4*)(x + flat);
    float4 r;
    r.x = xv.x + ov; r.y = xv.y + ov; r.z = xv.z + ov; r.w = xv.w + ov;
    *(float4*)(out + flat) = r;
}

extern "C" void kernel_launch(void* const* d_in, const int* in_sizes, int n_in,
                              void* d_out, int out_size, void* d_ws, size_t ws_size,
                              hipStream_t stream) {
    const float* x    = (const float*)d_in[0];
    const float* diff = (const float*)d_in[1];
    const float* Wq   = (const float*)d_in[2];
    const float* bq   = (const float*)d_in[3];
    const float* Wk   = (const float*)d_in[4];
    const float* bk   = (const float*)d_in[5];
    const float* Wv   = (const float*)d_in[6];
    const float* bv   = (const float*)d_in[7];
    float* ws = (float*)d_ws;
    // float arrays
    float* dpool  = ws;                    // 524288
    float* pxpool = ws + 524288;           // 524288
    float* op     = ws + 1048576;          // 524288
    // f16 arrays (each 524288 halves = 262144 floats)
    _Float16* qt  = (_Float16*)(ws + 1572864);
    _Float16* kt  = (_Float16*)(ws + 1835008);
    _Float16* vct = (_Float16*)(ws + 2097152);
    float* out = (float*)d_out;

    hipLaunchKernelGGL(k_pool, dim3(32768), dim3(256), 0, stream, x, diff, dpool, pxpool);
    hipLaunchKernelGGL(k_proj, dim3(384), dim3(256), 0, stream, dpool, pxpool,
                       Wq, bq, Wk, bk, Wv, bv, qt, kt, vct);
    hipLaunchKernelGGL(k_attn, dim3(512), dim3(256), 0, stream, qt, kt, vct, op);
    hipLaunchKernelGGL(k_out, dim3(32768), dim3(256), 0, stream, x, op, out);
}

// Round 3
// 127.580 us; speedup vs baseline: 1.9044x; 1.0587x over previous
//
#include <hip/hip_runtime.h>

#define BB 8
#define CC 64
#define HH 256
#define WW 256
#define DSF 8
#define HP 32
#define WP 32
#define NN 1024  // HP*WP

typedef _Float16 f16x4 __attribute__((ext_vector_type(4)));
typedef float f32x4 __attribute__((ext_vector_type(4)));

// ---------------------------------------------------------------------------
// K1: 8x8 avg-pool, streaming, no LDS, no barriers.
// 1024 blocks: bid<512 -> diff, else x. Block = one (b,c) plane (64KB).
// Wave w owns pooled rows [8w, 8w+8); per pooled row: 8 coalesced 1KB row
// loads (unroll 2 -> 16 in flight), in-register reduce + shfl_xor pair sum.
// ---------------------------------------------------------------------------
__global__ __launch_bounds__(256) void k_pool(const float* __restrict__ x,
                                              const float* __restrict__ diff,
                                              float* __restrict__ dpool,
                                              float* __restrict__ pxpool) {
    int bid = blockIdx.x;
    int which = bid >> 9;             // 0 = diff, 1 = x
    int plane = bid & 511;            // b*CC + c
    const float* base = (which ? x : diff) + (size_t)plane * (HH * WW);
    float* dst = (which ? pxpool : dpool) + (size_t)plane * NN;
    int t = threadIdx.x;
    int w = t >> 6, lane = t & 63;
    if (which) {
#pragma unroll 2
        for (int pr = 0; pr < 8; ++pr) {
            int row0 = (w * 8 + pr) * 8;
            float4 r[8];
#pragma unroll
            for (int rr = 0; rr < 8; ++rr)
                r[rr] = *(const float4*)(base + (size_t)(row0 + rr) * WW + lane * 4);
            float s = 0.f;
#pragma unroll
            for (int rr = 0; rr < 8; ++rr)
                s += (r[rr].x + r[rr].y) + (r[rr].z + r[rr].w);
            s += __shfl_xor(s, 1);
            if ((lane & 1) == 0)
                dst[(w * 8 + pr) * 32 + (lane >> 1)] = s * (1.f / 64.f);
        }
    } else {
        // diff is read exactly once -> non-temporal, keep x resident in L3
#pragma unroll 2
        for (int pr = 0; pr < 8; ++pr) {
            int row0 = (w * 8 + pr) * 8;
            f32x4 r[8];
#pragma unroll
            for (int rr = 0; rr < 8; ++rr)
                r[rr] = __builtin_nontemporal_load(
                    (const f32x4*)(base + (size_t)(row0 + rr) * WW + lane * 4));
            float s = 0.f;
#pragma unroll
            for (int rr = 0; rr < 8; ++rr)
                s += (r[rr][0] + r[rr][1]) + (r[rr][2] + r[rr][3]);
            s += __shfl_xor(s, 1);
            if ((lane & 1) == 0)
                dst[(w * 8 + pr) * 32 + (lane >> 1)] = s * (1.f / 64.f);
        }
    }
}

// ---------------------------------------------------------------------------
// K2: projections -> f16 in MFMA-friendly layouts (unchanged from R1).
// ---------------------------------------------------------------------------
__global__ __launch_bounds__(256) void k_proj(const float* __restrict__ dpool,
                                              const float* __restrict__ pxpool,
                                              const float* __restrict__ Wq, const float* __restrict__ bq,
                                              const float* __restrict__ Wk, const float* __restrict__ bk,
                                              const float* __restrict__ Wv, const float* __restrict__ bv,
                                              _Float16* __restrict__ qt, _Float16* __restrict__ kt,
                                              _Float16* __restrict__ vct) {
    __shared__ float Ws[64 * 65];
    __shared__ float dsh[64 * 68];
    int bid = blockIdx.x;
    int proj = bid >> 7;
    int rem = bid & 127;
    int b = rem >> 4;
    int n0 = (rem & 15) * 64;
    const float* Wm; const float* bias; const float* src;
    if (proj == 0)      { Wm = Wq; bias = bq; src = dpool; }
    else if (proj == 1) { Wm = Wk; bias = bk; src = dpool; }
    else                { Wm = Wv; bias = bv; src = pxpool; }
    int t = threadIdx.x;
#pragma unroll
    for (int i = 0; i < 16; ++i) {
        int e = t + i * 256;
        int o = e >> 6, c = e & 63;
        Ws[o * 65 + c] = Wm[e];
        dsh[o * 68 + c] = src[(size_t)(b * CC + o) * NN + n0 + c];
    }
    __syncthreads();
    int o = t & 63;
    int ng = t >> 6;
    float bb = bias[o];
    float4 acc[4];
#pragma unroll
    for (int j = 0; j < 4; ++j) acc[j] = make_float4(bb, bb, bb, bb);
#pragma unroll 8
    for (int c = 0; c < 64; ++c) {
        float wv = Ws[o * 65 + c];
        const float4* dr = (const float4*)(dsh + c * 68 + ng * 16);
#pragma unroll
        for (int j = 0; j < 4; ++j) {
            float4 d4 = dr[j];
            acc[j].x += wv * d4.x; acc[j].y += wv * d4.y;
            acc[j].z += wv * d4.z; acc[j].w += wv * d4.w;
        }
    }
    if (proj == 2) {
        _Float16* outp = vct + (size_t)(b * CC + o) * NN + n0 + ng * 16;
#pragma unroll
        for (int j = 0; j < 4; ++j) {
            f16x4 h;
            h[0] = (_Float16)acc[j].x; h[1] = (_Float16)acc[j].y;
            h[2] = (_Float16)acc[j].z; h[3] = (_Float16)acc[j].w;
            *(f16x4*)(outp + 4 * j) = h;
        }
    } else {
        __syncthreads();
#pragma unroll
        for (int j = 0; j < 4; ++j)
            *(float4*)(&dsh[o * 68 + ng * 16 + 4 * j]) = acc[j];
        __syncthreads();
        int nl = t & 63, og = t >> 6;
        float scale = (proj == 0) ? 0.125f : 1.0f;
        _Float16* outp = (proj == 0 ? qt : kt) + (size_t)(b * NN + n0 + nl) * CC + og * 16;
#pragma unroll
        for (int jj = 0; jj < 4; ++jj) {
            f16x4 h;
#pragma unroll
            for (int q4 = 0; q4 < 4; ++q4)
                h[q4] = (_Float16)(dsh[(og * 16 + 4 * jj + q4) * 68 + nl] * scale);
            *(f16x4*)(outp + 4 * jj) = h;
        }
    }
}

// ---------------------------------------------------------------------------
// K3: MFMA attention (unchanged from R1). One block = (b, 16-query tile).
// ---------------------------------------------------------------------------
__global__ __launch_bounds__(256) void k_attn(const _Float16* __restrict__ qt,
                                              const _Float16* __restrict__ kt,
                                              const _Float16* __restrict__ vct,
                                              float* __restrict__ op) {
#define PS 1036
    __shared__ __align__(16) _Float16 P[16 * PS];
    __shared__ float part[4 * 16 * 65];
    __shared__ float wmax[4][16];
    __shared__ float wsum[4][16];
    int bid = blockIdx.x;
    int b = bid >> 6;
    int n0 = (bid & 63) * 16;
    int t = threadIdx.x;
    int w = t >> 6, l = t & 63;
    int lo = l & 15, g = l >> 4;

    const _Float16* qb = qt + (size_t)(b * NN + n0) * CC;
    const _Float16* kb = kt + (size_t)b * NN * CC;
    const _Float16* vb = vct + (size_t)b * CC * NN;

    f16x4 aq[4];
#pragma unroll
    for (int kc = 0; kc < 4; ++kc)
        aq[kc] = *(const f16x4*)(qb + lo * CC + 16 * kc + 4 * g);

    int mbase = w * 256;
    f32x4 e[16];
#pragma unroll
    for (int tm = 0; tm < 16; ++tm) e[tm] = (f32x4){0.f, 0.f, 0.f, 0.f};
#pragma unroll
    for (int tm = 0; tm < 16; ++tm) {
        int m = mbase + 16 * tm + lo;
        const _Float16* kr = kb + (size_t)m * CC + 4 * g;
#pragma unroll
        for (int kc = 0; kc < 4; ++kc) {
            f16x4 bk = *(const f16x4*)(kr + 16 * kc);
            e[tm] = __builtin_amdgcn_mfma_f32_16x16x16f16(aq[kc], bk, e[tm], 0, 0, 0);
        }
    }
    float mx[4], sm[4];
#pragma unroll
    for (int r = 0; r < 4; ++r) {
        float m_ = -1e30f;
#pragma unroll
        for (int tm = 0; tm < 16; ++tm) m_ = fmaxf(m_, e[tm][r]);
#pragma unroll
        for (int off = 8; off; off >>= 1) m_ = fmaxf(m_, __shfl_xor(m_, off));
        mx[r] = m_;
    }
    if (lo == 0) {
#pragma unroll
        for (int r = 0; r < 4; ++r) wmax[w][4 * g + r] = mx[r];
    }
    __syncthreads();
#pragma unroll
    for (int r = 0; r < 4; ++r) {
        int n = 4 * g + r;
        mx[r] = fmaxf(fmaxf(wmax[0][n], wmax[1][n]), fmaxf(wmax[2][n], wmax[3][n]));
        sm[r] = 0.f;
    }
#pragma unroll
    for (int tm = 0; tm < 16; ++tm) {
        int mcol = mbase + 16 * tm + lo;
#pragma unroll
        for (int r = 0; r < 4; ++r) {
            float p = __expf(e[tm][r] - mx[r]);
            sm[r] += p;
            P[(4 * g + r) * PS + mcol] = (_Float16)p;
        }
    }
#pragma unroll
    for (int r = 0; r < 4; ++r) {
#pragma unroll
        for (int off = 8; off; off >>= 1) sm[r] += __shfl_xor(sm[r], off);
    }
    if (lo == 0) {
#pragma unroll
        for (int r = 0; r < 4; ++r) wsum[w][4 * g + r] = sm[r];
    }
    f32x4 o4[4];
#pragma unroll
    for (int tc = 0; tc < 4; ++tc) o4[tc] = (f32x4){0.f, 0.f, 0.f, 0.f};
#pragma unroll
    for (int mk = 0; mk < 16; ++mk) {
        f16x4 pa = *(const f16x4*)(&P[lo * PS + mbase + 16 * mk + 4 * g]);
        const _Float16* vr = vb + mbase + 16 * mk + 4 * g;
#pragma unroll
        for (int tc = 0; tc < 4; ++tc) {
            f16x4 bv_ = *(const f16x4*)(vr + (size_t)(lo + 16 * tc) * NN);
            o4[tc] = __builtin_amdgcn_mfma_f32_16x16x16f16(pa, bv_, o4[tc], 0, 0, 0);
        }
    }
#pragma unroll
    for (int tc = 0; tc < 4; ++tc)
#pragma unroll
        for (int r = 0; r < 4; ++r)
            part[(w * 16 + 4 * g + r) * 65 + lo + 16 * tc] = o4[tc][r];
    __syncthreads();
#pragma unroll
    for (int i = 0; i < 4; ++i) {
        int e2 = t + i * 256;
        int c = e2 >> 4, n = e2 & 15;
        float s = part[(0 * 16 + n) * 65 + c] + part[(1 * 16 + n) * 65 + c] +
                  part[(2 * 16 + n) * 65 + c] + part[(3 * 16 + n) * 65 + c];
        float denom = wsum[0][n] + wsum[1][n] + wsum[2][n] + wsum[3][n];
        op[(size_t)(b * CC + c) * NN + n0 + n] = s / denom;
    }
#undef PS
}

// ---------------------------------------------------------------------------
// K4: out = nearest-upsample(op, 8) + x. 2 coalesced float4 per thread,
// non-temporal store (out is never re-read).
// ---------------------------------------------------------------------------
__global__ __launch_bounds__(256) void k_out(const float* __restrict__ x,
                                             const float* __restrict__ op,
                                             float* __restrict__ out) {
    int t = threadIdx.x;
#pragma unroll
    for (int i = 0; i < 2; ++i) {
        size_t idx4 = (size_t)blockIdx.x * 512 + i * 256 + t;
        size_t flat = idx4 * 4;
        int w = (int)(flat & 255);
        int h = (int)((flat >> 8) & 255);
        int bc = (int)(flat >> 16);
        float ov = op[(size_t)bc * NN + (h >> 3) * WP + (w >> 3)];
        float4 xv = *(const float4*)(x + flat);
        f32x4 r = {xv.x + ov, xv.y + ov, xv.z + ov, xv.w + ov};
        __builtin_nontemporal_store(r, (f32x4*)(out + flat));
    }
}

extern "C" void kernel_launch(void* const* d_in, const int* in_sizes, int n_in,
                              void* d_out, int out_size, void* d_ws, size_t ws_size,
                              hipStream_t stream) {
    const float* x    = (const float*)d_in[0];
    const float* diff = (const float*)d_in[1];
    const float* Wq   = (const float*)d_in[2];
    const float* bq   = (const float*)d_in[3];
    const float* Wk   = (const float*)d_in[4];
    const float* bk   = (const float*)d_in[5];
    const float* Wv   = (const float*)d_in[6];
    const float* bv   = (const float*)d_in[7];
    float* ws = (float*)d_ws;
    float* dpool  = ws;                    // 524288 floats
    float* pxpool = ws + 524288;
    float* op     = ws + 1048576;
    _Float16* qt  = (_Float16*)(ws + 1572864);
    _Float16* kt  = (_Float16*)(ws + 1835008);
    _Float16* vct = (_Float16*)(ws + 2097152);
    float* out = (float*)d_out;

    hipLaunchKernelGGL(k_pool, dim3(1024), dim3(256), 0, stream, x, diff, dpool, pxpool);
    hipLaunchKernelGGL(k_proj, dim3(384), dim3(256), 0, stream, dpool, pxpool,
                       Wq, bq, Wk, bk, Wv, bv, qt, kt, vct);
    hipLaunchKernelGGL(k_attn, dim3(512), dim3(256), 0, stream, qt, kt, vct, op);
    hipLaunchKernelGGL(k_out, dim3(16384), dim3(256), 0, stream, x, op, out);
}

// Round 4
// 122.184 us; speedup vs baseline: 1.9885x; 1.0442x over previous
//
#include <hip/hip_runtime.h>

#define BB 8
#define CC 64
#define HH 256
#define WW 256
#define DSF 8
#define HP 32
#define WP 32
#define NN 1024  // HP*WP

typedef _Float16 f16x4 __attribute__((ext_vector_type(4)));
typedef float f32x4 __attribute__((ext_vector_type(4)));

// ---------------------------------------------------------------------------
// K1: 8x8 avg-pool, streaming, no LDS, no barriers.
// 4096 blocks = (src, b, c, rowgroup). Block covers 8 pooled rows (64 input
// rows, 64KB). Wave w owns pooled rows {2w, 2w+1} of the group: 16 consecutive
// input rows loaded as ONE 16-load burst (16KB/wave in flight), then reduced.
// ---------------------------------------------------------------------------
__global__ __launch_bounds__(256) void k_pool(const float* __restrict__ x,
                                              const float* __restrict__ diff,
                                              float* __restrict__ dpool,
                                              float* __restrict__ pxpool) {
    int bid = blockIdx.x;
    int which = bid >> 11;            // 0 = diff, 1 = x
    int r = bid & 2047;
    int g = r & 3;                    // row-group
    int c = (r >> 2) & 63;
    int b = r >> 8;
    int plane = b * CC + c;
    const float* base = (which ? x : diff) + (size_t)plane * (HH * WW);
    float* dst = (which ? pxpool : dpool) + (size_t)plane * NN;
    int t = threadIdx.x;
    int w = t >> 6, lane = t & 63;
    int pr0 = g * 8 + 2 * w;          // first pooled row of this wave
    int row0 = pr0 * 8;               // first input row (16 consecutive rows)
    const float* rb = base + (size_t)row0 * WW + lane * 4;

    f32x4 r16[16];
    if (which) {
#pragma unroll
        for (int i = 0; i < 16; ++i)
            r16[i] = *(const f32x4*)(rb + (size_t)i * WW);
    } else {
        // diff is read exactly once -> non-temporal, keep x resident in L3
#pragma unroll
        for (int i = 0; i < 16; ++i)
            r16[i] = __builtin_nontemporal_load((const f32x4*)(rb + (size_t)i * WW));
    }
    float s0 = 0.f, s1 = 0.f;
#pragma unroll
    for (int i = 0; i < 8; ++i)
        s0 += (r16[i][0] + r16[i][1]) + (r16[i][2] + r16[i][3]);
#pragma unroll
    for (int i = 8; i < 16; ++i)
        s1 += (r16[i][0] + r16[i][1]) + (r16[i][2] + r16[i][3]);
    s0 += __shfl_xor(s0, 1);
    s1 += __shfl_xor(s1, 1);
    if ((lane & 1) == 0) {
        dst[pr0 * 32 + (lane >> 1)] = s0 * (1.f / 64.f);
        dst[(pr0 + 1) * 32 + (lane >> 1)] = s1 * (1.f / 64.f);
    }
}

// ---------------------------------------------------------------------------
// K2: projections -> f16 in MFMA-friendly layouts (unchanged).
// ---------------------------------------------------------------------------
__global__ __launch_bounds__(256) void k_proj(const float* __restrict__ dpool,
                                              const float* __restrict__ pxpool,
                                              const float* __restrict__ Wq, const float* __restrict__ bq,
                                              const float* __restrict__ Wk, const float* __restrict__ bk,
                                              const float* __restrict__ Wv, const float* __restrict__ bv,
                                              _Float16* __restrict__ qt, _Float16* __restrict__ kt,
                                              _Float16* __restrict__ vct) {
    __shared__ float Ws[64 * 65];
    __shared__ float dsh[64 * 68];
    int bid = blockIdx.x;
    int proj = bid >> 7;
    int rem = bid & 127;
    int b = rem >> 4;
    int n0 = (rem & 15) * 64;
    const float* Wm; const float* bias; const float* src;
    if (proj == 0)      { Wm = Wq; bias = bq; src = dpool; }
    else if (proj == 1) { Wm = Wk; bias = bk; src = dpool; }
    else                { Wm = Wv; bias = bv; src = pxpool; }
    int t = threadIdx.x;
#pragma unroll
    for (int i = 0; i < 16; ++i) {
        int e = t + i * 256;
        int o = e >> 6, c = e & 63;
        Ws[o * 65 + c] = Wm[e];
        dsh[o * 68 + c] = src[(size_t)(b * CC + o) * NN + n0 + c];
    }
    __syncthreads();
    int o = t & 63;
    int ng = t >> 6;
    float bb = bias[o];
    float4 acc[4];
#pragma unroll
    for (int j = 0; j < 4; ++j) acc[j] = make_float4(bb, bb, bb, bb);
#pragma unroll 8
    for (int c = 0; c < 64; ++c) {
        float wv = Ws[o * 65 + c];
        const float4* dr = (const float4*)(dsh + c * 68 + ng * 16);
#pragma unroll
        for (int j = 0; j < 4; ++j) {
            float4 d4 = dr[j];
            acc[j].x += wv * d4.x; acc[j].y += wv * d4.y;
            acc[j].z += wv * d4.z; acc[j].w += wv * d4.w;
        }
    }
    if (proj == 2) {
        _Float16* outp = vct + (size_t)(b * CC + o) * NN + n0 + ng * 16;
#pragma unroll
        for (int j = 0; j < 4; ++j) {
            f16x4 h;
            h[0] = (_Float16)acc[j].x; h[1] = (_Float16)acc[j].y;
            h[2] = (_Float16)acc[j].z; h[3] = (_Float16)acc[j].w;
            *(f16x4*)(outp + 4 * j) = h;
        }
    } else {
        __syncthreads();
#pragma unroll
        for (int j = 0; j < 4; ++j)
            *(float4*)(&dsh[o * 68 + ng * 16 + 4 * j]) = acc[j];
        __syncthreads();
        int nl = t & 63, og = t >> 6;
        float scale = (proj == 0) ? 0.125f : 1.0f;
        _Float16* outp = (proj == 0 ? qt : kt) + (size_t)(b * NN + n0 + nl) * CC + og * 16;
#pragma unroll
        for (int jj = 0; jj < 4; ++jj) {
            f16x4 h;
#pragma unroll
            for (int q4 = 0; q4 < 4; ++q4)
                h[q4] = (_Float16)(dsh[(og * 16 + 4 * jj + q4) * 68 + nl] * scale);
            *(f16x4*)(outp + 4 * jj) = h;
        }
    }
}

// ---------------------------------------------------------------------------
// K3: MFMA attention (unchanged). One block = (b, 16-query tile).
// ---------------------------------------------------------------------------
__global__ __launch_bounds__(256) void k_attn(const _Float16* __restrict__ qt,
                                              const _Float16* __restrict__ kt,
                                              const _Float16* __restrict__ vct,
                                              float* __restrict__ op) {
#define PS 1036
    __shared__ __align__(16) _Float16 P[16 * PS];
    __shared__ float part[4 * 16 * 65];
    __shared__ float wmax[4][16];
    __shared__ float wsum[4][16];
    int bid = blockIdx.x;
    int b = bid >> 6;
    int n0 = (bid & 63) * 16;
    int t = threadIdx.x;
    int w = t >> 6, l = t & 63;
    int lo = l & 15, g = l >> 4;

    const _Float16* qb = qt + (size_t)(b * NN + n0) * CC;
    const _Float16* kb = kt + (size_t)b * NN * CC;
    const _Float16* vb = vct + (size_t)b * CC * NN;

    f16x4 aq[4];
#pragma unroll
    for (int kc = 0; kc < 4; ++kc)
        aq[kc] = *(const f16x4*)(qb + lo * CC + 16 * kc + 4 * g);

    int mbase = w * 256;
    f32x4 e[16];
#pragma unroll
    for (int tm = 0; tm < 16; ++tm) e[tm] = (f32x4){0.f, 0.f, 0.f, 0.f};
#pragma unroll
    for (int tm = 0; tm < 16; ++tm) {
        int m = mbase + 16 * tm + lo;
        const _Float16* kr = kb + (size_t)m * CC + 4 * g;
#pragma unroll
        for (int kc = 0; kc < 4; ++kc) {
            f16x4 bk = *(const f16x4*)(kr + 16 * kc);
            e[tm] = __builtin_amdgcn_mfma_f32_16x16x16f16(aq[kc], bk, e[tm], 0, 0, 0);
        }
    }
    float mx[4], sm[4];
#pragma unroll
    for (int r = 0; r < 4; ++r) {
        float m_ = -1e30f;
#pragma unroll
        for (int tm = 0; tm < 16; ++tm) m_ = fmaxf(m_, e[tm][r]);
#pragma unroll
        for (int off = 8; off; off >>= 1) m_ = fmaxf(m_, __shfl_xor(m_, off));
        mx[r] = m_;
    }
    if (lo == 0) {
#pragma unroll
        for (int r = 0; r < 4; ++r) wmax[w][4 * g + r] = mx[r];
    }
    __syncthreads();
#pragma unroll
    for (int r = 0; r < 4; ++r) {
        int n = 4 * g + r;
        mx[r] = fmaxf(fmaxf(wmax[0][n], wmax[1][n]), fmaxf(wmax[2][n], wmax[3][n]));
        sm[r] = 0.f;
    }
#pragma unroll
    for (int tm = 0; tm < 16; ++tm) {
        int mcol = mbase + 16 * tm + lo;
#pragma unroll
        for (int r = 0; r < 4; ++r) {
            float p = __expf(e[tm][r] - mx[r]);
            sm[r] += p;
            P[(4 * g + r) * PS + mcol] = (_Float16)p;
        }
    }
#pragma unroll
    for (int r = 0; r < 4; ++r) {
#pragma unroll
        for (int off = 8; off; off >>= 1) sm[r] += __shfl_xor(sm[r], off);
    }
    if (lo == 0) {
#pragma unroll
        for (int r = 0; r < 4; ++r) wsum[w][4 * g + r] = sm[r];
    }
    f32x4 o4[4];
#pragma unroll
    for (int tc = 0; tc < 4; ++tc) o4[tc] = (f32x4){0.f, 0.f, 0.f, 0.f};
#pragma unroll
    for (int mk = 0; mk < 16; ++mk) {
        f16x4 pa = *(const f16x4*)(&P[lo * PS + mbase + 16 * mk + 4 * g]);
        const _Float16* vr = vb + mbase + 16 * mk + 4 * g;
#pragma unroll
        for (int tc = 0; tc < 4; ++tc) {
            f16x4 bv_ = *(const f16x4*)(vr + (size_t)(lo + 16 * tc) * NN);
            o4[tc] = __builtin_amdgcn_mfma_f32_16x16x16f16(pa, bv_, o4[tc], 0, 0, 0);
        }
    }
#pragma unroll
    for (int tc = 0; tc < 4; ++tc)
#pragma unroll
        for (int r = 0; r < 4; ++r)
            part[(w * 16 + 4 * g + r) * 65 + lo + 16 * tc] = o4[tc][r];
    __syncthreads();
#pragma unroll
    for (int i = 0; i < 4; ++i) {
        int e2 = t + i * 256;
        int c = e2 >> 4, n = e2 & 15;
        float s = part[(0 * 16 + n) * 65 + c] + part[(1 * 16 + n) * 65 + c] +
                  part[(2 * 16 + n) * 65 + c] + part[(3 * 16 + n) * 65 + c];
        float denom = wsum[0][n] + wsum[1][n] + wsum[2][n] + wsum[3][n];
        op[(size_t)(b * CC + c) * NN + n0 + n] = s / denom;
    }
#undef PS
}

// ---------------------------------------------------------------------------
// K4: out = nearest-upsample(op, 8) + x. Coalesced float4, nt store.
// ---------------------------------------------------------------------------
__global__ __launch_bounds__(256) void k_out(const float* __restrict__ x,
                                             const float* __restrict__ op,
                                             float* __restrict__ out) {
    int t = threadIdx.x;
#pragma unroll
    for (int i = 0; i < 2; ++i) {
        size_t idx4 = (size_t)blockIdx.x * 512 + i * 256 + t;
        size_t flat = idx4 * 4;
        int w = (int)(flat & 255);
        int h = (int)((flat >> 8) & 255);
        int bc = (int)(flat >> 16);
        float ov = op[(size_t)bc * NN + (h >> 3) * WP + (w >> 3)];
        float4 xv = *(const float4*)(x + flat);
        f32x4 r = {xv.x + ov, xv.y + ov, xv.z + ov, xv.w + ov};
        __builtin_nontemporal_store(r, (f32x4*)(out + flat));
    }
}

extern "C" void kernel_launch(void* const* d_in, const int* in_sizes, int n_in,
                              void* d_out, int out_size, void* d_ws, size_t ws_size,
                              hipStream_t stream) {
    const float* x    = (const float*)d_in[0];
    const float* diff = (const float*)d_in[1];
    const float* Wq   = (const float*)d_in[2];
    const float* bq   = (const float*)d_in[3];
    const float* Wk   = (const float*)d_in[4];
    const float* bk   = (const float*)d_in[5];
    const float* Wv   = (const float*)d_in[6];
    const float* bv   = (const float*)d_in[7];
    float* ws = (float*)d_ws;
    float* dpool  = ws;                    // 524288 floats
    float* pxpool = ws + 524288;
    float* op     = ws + 1048576;
    _Float16* qt  = (_Float16*)(ws + 1572864);
    _Float16* kt  = (_Float16*)(ws + 1835008);
    _Float16* vct = (_Float16*)(ws + 2097152);
    float* out = (float*)d_out;

    hipLaunchKernelGGL(k_pool, dim3(4096), dim3(256), 0, stream, x, diff, dpool, pxpool);
    hipLaunchKernelGGL(k_proj, dim3(384), dim3(256), 0, stream, dpool, pxpool,
                       Wq, bq, Wk, bk, Wv, bv, qt, kt, vct);
    hipLaunchKernelGGL(k_attn, dim3(512), dim3(256), 0, stream, qt, kt, vct, op);
    hipLaunchKernelGGL(k_out, dim3(16384), dim3(256), 0, stream, x, op, out);
}